// Round 5
// baseline (113.366 us; speedup 1.0000x reference)
//
#include <hip/hip_runtime.h>
#include <hip/hip_bf16.h>

#define N_ROWS 4096
#define TWO_N  8192
#define ZDIM   256
#define INV_T  (1.0f/0.07f)
// exp((s-1)/T) = exp2((s-1) * INV_T * log2(e))
#define EXP_SCALE (INV_T * 1.44269504088896340736f)

typedef __attribute__((ext_vector_type(8))) short bf16x8;   // 8 bf16 in 4 VGPRs
typedef __attribute__((ext_vector_type(4))) float f32x4;

__device__ __forceinline__ void async_load16(const void* g, void* lds_uniform_base) {
  // HW computes LDS dest = (wave-uniform base) + lane*16; pass base WITHOUT lane term.
  __builtin_amdgcn_global_load_lds(
      (const __attribute__((address_space(1))) void*)g,
      (__attribute__((address_space(3))) void*)lds_uniform_base, 16, 0, 0);
}

// ---------------- Kernel A: normalize rows -> bf16 reps, fp32 pos; init out=1/T --------
__global__ __launch_bounds__(256) void normalize_kernel(
    const float* __restrict__ z1, const float* __restrict__ z2,
    __hip_bfloat16* __restrict__ reps, float* __restrict__ pos,
    float* __restrict__ out) {
  const int b = blockIdx.x;
  const int t = threadIdx.x;
  const float x1 = z1[b * ZDIM + t];
  const float x2 = z2[b * ZDIM + t];
  float s1 = x1 * x1, s2 = x2 * x2, s3 = x1 * x2;
  #pragma unroll
  for (int m = 1; m < 64; m <<= 1) {
    s1 += __shfl_xor(s1, m, 64);
    s2 += __shfl_xor(s2, m, 64);
    s3 += __shfl_xor(s3, m, 64);
  }
  __shared__ float red[3][4];
  const int w = t >> 6, l = t & 63;
  if (l == 0) { red[0][w] = s1; red[1][w] = s2; red[2][w] = s3; }
  __syncthreads();
  const float n1 = red[0][0] + red[0][1] + red[0][2] + red[0][3];
  const float n2 = red[1][0] + red[1][1] + red[1][2] + red[1][3];
  const float dt = red[2][0] + red[2][1] + red[2][2] + red[2][3];
  const float inv1 = 1.0f / fmaxf(sqrtf(n1), 1e-12f);
  const float inv2 = 1.0f / fmaxf(sqrtf(n2), 1e-12f);
  reps[b * ZDIM + t]            = __float2bfloat16(x1 * inv1);
  reps[(b + N_ROWS) * ZDIM + t] = __float2bfloat16(x2 * inv2);
  if (t == 0) {
    pos[b] = dt * inv1 * inv2;
    if (b == 0) out[0] = INV_T;   // reduce_kernel atomically adds partials onto this
  }
}

// ---------------- Kernel B: triangular flash row/col partials, full-B single-stage ------
// sim symmetric: each unordered 128x128 tile-pair once. Row-tile i, chunk c in 0..3:
//   c==0: d = {0(diag),1..7} (+32 if i<32);  c>0: d = {8c..8c+7};  j=(i+d)&63.
// A tile (128x256, 64KB) staged once; B tile (128x256, 64KB) staged whole per off-diag
// tile -> ONE vmcnt drain + 3 barriers per tile (vs 10 with K-chunked B). 130KB LDS ->
// 1 block/CU; grid (64,4) = 256 blocks = exactly 1/CU, fully resident.
// Row sums -> rowscratch[i][c][128] (wn-halves merged via LDS: both wn waves cover the
// SAME rows — plain per-wave stores would race). Col sums -> colscratch[j][d-1][128],
// each slot written by exactly one block (plain stores, zero atomics).
__global__ __launch_bounds__(256, 1) void simsum_kernel(
    const __hip_bfloat16* __restrict__ reps,
    float* __restrict__ rowscratch,   // [64][4][128]
    float* __restrict__ colscratch) { // [64][32][128]
  __shared__ __align__(16) __hip_bfloat16 Alds[128 * 256];  // 64 KB
  __shared__ __align__(16) __hip_bfloat16 Blds[128 * 256];  // 64 KB
  __shared__ float colred[2][256];                          // 2 KB, dbuf by tile parity

  const int tid  = threadIdx.x;
  const int lane = tid & 63;
  const int wave = tid >> 6;
  const int wm = wave >> 1, wn = wave & 1;   // 2x2 wave grid
  const int quad = lane >> 4;                // 0..3
  const int l16  = lane & 15;
  const int itile = blockIdx.x;              // row tile 0..63
  const int chunk = blockIdx.y;              // distance chunk 0..3
  const int rowBase = itile * 128;
  const char* gbase = (const char*)reps;

  // Stage A tile: rows [rowBase,+128), K=256. LDS 16B-chunk c holds global chunk with
  // low-3-bits XOR'd by row (conflict-min ds_read_b128).
  #pragma unroll
  for (int p = 0; p < 16; ++p) {
    const int cbase = p * 256 + (wave << 6);
    const int c = cbase + lane;
    const int row = c >> 5;                 // 32 chunks per 512B row
    const int ch = (c & 31) ^ (row & 7);
    async_load16(gbase + ((rowBase + row) * ZDIM + ch * 8) * 2,
                 (char*)Alds + cbase * 16);
  }
  __syncthreads();  // drain A (needed before diag tile's Alds B-operand reads)

  const int nd = (chunk == 0) ? ((itile < 32) ? 9 : 8) : 8;

  float rowpart[16];
  #pragma unroll
  for (int i = 0; i < 16; ++i) rowpart[i] = 0.0f;

  const f32x4 zero4 = {0.0f, 0.0f, 0.0f, 0.0f};

  for (int td = 0; td < nd; ++td) {
    const int d = (chunk == 0) ? ((td == 8) ? 32 : td) : (chunk * 8 + td);
    const int jtile = (itile + d) & 63;
    const int colBase = jtile * 128;
    const bool diag = (d == 0);

    if (!diag) {
      __syncthreads();   // prior tile's Blds k-reads + colred combine-reads complete
      #pragma unroll
      for (int p = 0; p < 16; ++p) {
        const int cbase = p * 256 + (wave << 6);
        const int c = cbase + lane;
        const int row = c >> 5;
        const int ch = (c & 31) ^ (row & 7);
        async_load16(gbase + ((colBase + row) * ZDIM + ch * 8) * 2,
                     (char*)Blds + cbase * 16);
      }
      __syncthreads();   // drain B (vmcnt(0) before s_barrier)
    }

    f32x4 acc[4][4];
    #pragma unroll
    for (int mi = 0; mi < 4; ++mi)
      #pragma unroll
      for (int ni = 0; ni < 4; ++ni) acc[mi][ni] = zero4;

    // 8 straight-line k-steps: no barriers, only compiler lgkmcnt between ds_read & MFMA
    #pragma unroll
    for (int kc = 0; kc < 4; ++kc) {
      #pragma unroll
      for (int kk2 = 0; kk2 < 2; ++kk2) {
        const int CH = kc * 8 + kk2 * 4 + quad;   // chunk in [0,32)
        bf16x8 afrag[4], bfrag[4];
        #pragma unroll
        for (int mi = 0; mi < 4; ++mi) {
          const int m = wm * 64 + mi * 16 + l16;
          afrag[mi] = *(const bf16x8*)((const char*)Alds + (m * 32 + (CH ^ (m & 7))) * 16);
        }
        #pragma unroll
        for (int ni = 0; ni < 4; ++ni) {
          const int n = wn * 64 + ni * 16 + l16;
          const char* src = diag ? (const char*)Alds : (const char*)Blds;
          bfrag[ni] = *(const bf16x8*)(src + (n * 32 + (CH ^ (n & 7))) * 16);
        }
        #pragma unroll
        for (int mi = 0; mi < 4; ++mi)
          #pragma unroll
          for (int ni = 0; ni < 4; ++ni)
            acc[mi][ni] = __builtin_amdgcn_mfma_f32_16x16x32_bf16(
                afrag[mi], bfrag[ni], acc[mi][ni], 0, 0, 0);
      }
    }

    // Epilogue: e = exp((s-1)/T). Rows -> rowpart regs; cols -> colred (dedicated LDS,
    // parity-double-buffered) -> one plain colscratch store per element.
    float colpart[4] = {0.0f, 0.0f, 0.0f, 0.0f};
    #pragma unroll
    for (int mi = 0; mi < 4; ++mi) {
      #pragma unroll
      for (int r = 0; r < 4; ++r) {
        const int grow = rowBase + wm * 64 + mi * 16 + quad * 4 + r;
        float s = 0.0f;
        #pragma unroll
        for (int ni = 0; ni < 4; ++ni) {
          const int gcol = colBase + wn * 64 + ni * 16 + l16;
          const float v = acc[mi][ni][r];
          const float e = exp2f((v - 1.0f) * EXP_SCALE);
          if (!diag || grow != gcol) s += e;
          colpart[ni] += e;
        }
        rowpart[mi * 4 + r] += s;
      }
    }
    if (!diag) {
      #pragma unroll
      for (int ni = 0; ni < 4; ++ni) {
        float v = colpart[ni];
        v += __shfl_xor(v, 16, 64);   // reduce across the 4 quads (frag rows)
        v += __shfl_xor(v, 32, 64);
        if (quad == 0) colred[td & 1][wm * 128 + wn * 64 + ni * 16 + l16] = v;
      }
      __syncthreads();
      if (tid < 128)
        colscratch[(jtile * 32 + (d - 1)) * 128 + tid] =
            colred[td & 1][tid] + colred[td & 1][128 + tid];
      // no barrier here: next iter's top barrier orders combine-reads vs next writes
    }
  }

  // Row partials: shfl over the 16 column-lanes, then merge the two wn-half waves
  // (same rows, different column halves) through LDS — per-wave stores would race.
  #pragma unroll
  for (int i = 0; i < 16; ++i) {
    float v = rowpart[i];
    v += __shfl_xor(v, 1, 64);
    v += __shfl_xor(v, 2, 64);
    v += __shfl_xor(v, 4, 64);
    v += __shfl_xor(v, 8, 64);
    rowpart[i] = v;
  }
  __syncthreads();   // colred[0] free for reuse
  if (l16 == 0) {
    #pragma unroll
    for (int mi = 0; mi < 4; ++mi)
      #pragma unroll
      for (int r = 0; r < 4; ++r)
        colred[0][wn * 128 + wm * 64 + mi * 16 + quad * 4 + r] = rowpart[mi * 4 + r];
  }
  __syncthreads();
  if (tid < 128)
    rowscratch[(itile * 4 + chunk) * 128 + tid] = colred[0][tid] + colred[0][128 + tid];
}

// ---------------- Kernel C: gather partials per row, logf, add partial loss -------------
// Grid 64 blocks: block j handles rows [j*128,+128) and pos[j*64,+64).
// out was pre-set to 1/T by normalize; each block atomicAdds its partial (64 atomics).
__global__ __launch_bounds__(256) void reduce_kernel(
    const float* __restrict__ rowscratch, const float* __restrict__ colscratch,
    const float* __restrict__ pos, float* __restrict__ out) {
  const int j = blockIdx.x;
  const int tid = threadIdx.x;
  float v = 0.0f;
  if (tid < 128) {
    float s = 0.0f;
    #pragma unroll
    for (int c = 0; c < 4; ++c) s += rowscratch[(j * 4 + c) * 128 + tid];
    const int ns = (j < 32) ? 31 : 32;   // j<32: the d=32 pair arrived via rowscratch side
    for (int si = 0; si < ns; ++si) s += colscratch[(j * 32 + si) * 128 + tid];
    v = logf(s) * (1.0f / (float)TWO_N);
  } else if (tid < 192) {
    v = -pos[j * 64 + (tid - 128)] * (INV_T / (float)N_ROWS);
  }
  #pragma unroll
  for (int m = 1; m < 64; m <<= 1) v += __shfl_xor(v, m, 64);
  __shared__ float red[4];
  if ((tid & 63) == 0) red[tid >> 6] = v;
  __syncthreads();
  if (tid == 0) atomicAdd(out, red[0] + red[1] + red[2] + red[3]);
}

extern "C" void kernel_launch(void* const* d_in, const int* in_sizes, int n_in,
                              void* d_out, int out_size, void* d_ws, size_t ws_size,
                              hipStream_t stream) {
  const float* z1 = (const float*)d_in[0];
  const float* z2 = (const float*)d_in[1];
  char* ws = (char*)d_ws;
  __hip_bfloat16* reps = (__hip_bfloat16*)ws;              // 8192*256*2 = 4 MB
  size_t off = (size_t)TWO_N * ZDIM * 2;
  float* pos = (float*)(ws + off);        off += N_ROWS * 4;        // 16 KB
  float* rowscratch = (float*)(ws + off); off += 64 * 4 * 128 * 4;  // 128 KB
  float* colscratch = (float*)(ws + off); off += 64 * 32 * 128 * 4; // 1 MB

  normalize_kernel<<<N_ROWS, 256, 0, stream>>>(z1, z2, reps, pos, (float*)d_out);
  simsum_kernel<<<dim3(64, 4), 256, 0, stream>>>(reps, rowscratch, colscratch);
  reduce_kernel<<<64, 256, 0, stream>>>(rowscratch, colscratch, pos, (float*)d_out);
}

// Round 6
// 100.533 us; speedup vs baseline: 1.1276x; 1.1276x over previous
//
#include <hip/hip_runtime.h>
#include <hip/hip_bf16.h>

#define N_ROWS 4096
#define TWO_N  8192
#define ZDIM   256
#define INV_T  (1.0f/0.07f)
// exp((s-1)/T) = exp2((s-1) * INV_T * log2(e))
#define EXP_SCALE (INV_T * 1.44269504088896340736f)

typedef __attribute__((ext_vector_type(4))) float f32x4;

__device__ __forceinline__ void async_load16(const void* g, void* lds_uniform_base) {
  // HW computes LDS dest = (wave-uniform base) + lane*16; pass base WITHOUT lane term.
  __builtin_amdgcn_global_load_lds(
      (const __attribute__((address_space(1))) void*)g,
      (__attribute__((address_space(3))) void*)lds_uniform_base, 16, 0, 0);
}

// float -> OCP e4m3fn, round-to-nearest-even. Inputs here are |x| <= 1.
__device__ __forceinline__ unsigned char f32_to_e4m3(float x) {
  unsigned int u = __float_as_uint(x);
  const unsigned int s = u >> 31;
  unsigned int a = u & 0x7FFFFFFFu;
  if (a > 0x43E00000u) a = 0x43E00000u;          // clamp |x| <= 448 (unreachable here)
  const float f = __uint_as_float(a);
  unsigned int out;
  if (a < (121u << 23)) {                        // |x| < 2^-6: e4m3 subnormal, step 2^-9
    const int m = (int)rintf(f * 512.0f);        // 0..8 (8 rolls into exp=1 mant=0 = 2^-6)
    out = (unsigned int)m;
  } else {
    const unsigned int r = a + 0x7FFFFu + ((a >> 20) & 1u);  // RNE to 3 mantissa bits
    const unsigned int e8 = (r >> 23) - 120u;    // rebias 127 -> 7 (carry handled by r)
    out = (e8 << 3) | ((r >> 20) & 7u);
  }
  return (unsigned char)(out | (s << 7));
}

// ---------------- Kernel A: normalize rows -> fp8 reps, fp32 pos; init out=1/T ---------
__global__ __launch_bounds__(256) void normalize_kernel(
    const float* __restrict__ z1, const float* __restrict__ z2,
    unsigned char* __restrict__ reps, float* __restrict__ pos,
    float* __restrict__ out) {
  const int b = blockIdx.x;
  const int t = threadIdx.x;
  const float x1 = z1[b * ZDIM + t];
  const float x2 = z2[b * ZDIM + t];
  float s1 = x1 * x1, s2 = x2 * x2, s3 = x1 * x2;
  #pragma unroll
  for (int m = 1; m < 64; m <<= 1) {
    s1 += __shfl_xor(s1, m, 64);
    s2 += __shfl_xor(s2, m, 64);
    s3 += __shfl_xor(s3, m, 64);
  }
  __shared__ float red[3][4];
  const int w = t >> 6, l = t & 63;
  if (l == 0) { red[0][w] = s1; red[1][w] = s2; red[2][w] = s3; }
  __syncthreads();
  const float n1 = red[0][0] + red[0][1] + red[0][2] + red[0][3];
  const float n2 = red[1][0] + red[1][1] + red[1][2] + red[1][3];
  const float dt = red[2][0] + red[2][1] + red[2][2] + red[2][3];
  const float inv1 = 1.0f / fmaxf(sqrtf(n1), 1e-12f);
  const float inv2 = 1.0f / fmaxf(sqrtf(n2), 1e-12f);
  reps[b * ZDIM + t]            = f32_to_e4m3(x1 * inv1);
  reps[(b + N_ROWS) * ZDIM + t] = f32_to_e4m3(x2 * inv2);
  if (t == 0) {
    pos[b] = dt * inv1 * inv2;   // fp32-exact positives
    if (b == 0) out[0] = INV_T;  // reduce_kernel atomically adds partials onto this
  }
}

// ---------------- Kernel B: triangular fp8 flash row/col partials, full-B, 2 blocks/CU --
// sim symmetric: each unordered 128x128 tile-pair once. Row-tile i, chunk c in 0..7:
//   c==0: d={0(diag),1,2,3} (+32 if i<32); c>0: d={4c..4c+3}; j=(i+d)&63.
// fp8 halves bytes: A tile 128x256 = 32KB staged once; FULL B tile 32KB staged per
// off-diag tile (one drain + 3 barriers/tile). 66KB LDS -> 2 blocks/CU: sibling block
// covers drain/barrier stalls (round-5 lesson: 1 block/CU serializes the whole CU).
// Row sums -> rowscratch (wn-halves merged via LDS: both wn waves cover the SAME rows).
// Col sums -> colscratch[j][d-1][128], each slot written by exactly one block. No atomics.
__global__ __launch_bounds__(256, 2) void simsum_kernel(
    const unsigned char* __restrict__ reps,
    float* __restrict__ rowscratch,   // [64][8][128]
    float* __restrict__ colscratch) { // [64][32][128]
  __shared__ __align__(16) unsigned char Alds[128 * 256];  // 32 KB
  __shared__ __align__(16) unsigned char Blds[128 * 256];  // 32 KB
  __shared__ float colred[2][256];                         // 2 KB, dbuf by tile parity

  const int tid  = threadIdx.x;
  const int lane = tid & 63;
  const int wave = tid >> 6;
  const int wm = wave >> 1, wn = wave & 1;   // 2x2 wave grid
  const int quad = lane >> 4;                // 0..3
  const int l16  = lane & 15;
  const int itile = blockIdx.x;              // row tile 0..63
  const int chunk = blockIdx.y;              // distance chunk 0..7
  const int rowBase = itile * 128;
  const char* gbase = (const char*)reps;

  // Stage A tile: rows [rowBase,+128), K=256 fp8 (256B/row = 16 16B-chunks).
  // LDS 16B-chunk (row,k16) holds global k16' = (k16&8)|((k16^row)&7)  [XOR low3 swizzle]
  #pragma unroll
  for (int p = 0; p < 8; ++p) {
    const int c = p * 256 + (wave << 6) + lane;
    const int row = c >> 4, k16 = c & 15;
    const int src = (k16 & 8) | ((k16 ^ row) & 7);
    async_load16(gbase + (rowBase + row) * ZDIM + src * 16,
                 (char*)Alds + (size_t)c * 16 - (size_t)lane * 16 + (size_t)lane * 16);
  }
  __syncthreads();  // drain A (needed before diag tile's Alds B-operand reads)

  const int nd = (chunk == 0) ? ((itile < 32) ? 5 : 4) : 4;

  float rowpart[16];
  #pragma unroll
  for (int i = 0; i < 16; ++i) rowpart[i] = 0.0f;

  const f32x4 zero4 = {0.0f, 0.0f, 0.0f, 0.0f};

  for (int td = 0; td < nd; ++td) {
    const int d = (chunk == 0) ? ((td == 4) ? 32 : td) : (chunk * 4 + td);
    const int jtile = (itile + d) & 63;
    const int colBase = jtile * 128;
    const bool diag = (d == 0);

    if (!diag) {
      __syncthreads();   // prior tile's Blds k-reads + colred combine-reads complete
      #pragma unroll
      for (int p = 0; p < 8; ++p) {
        const int c = p * 256 + (wave << 6) + lane;
        const int row = c >> 4, k16 = c & 15;
        const int src = (k16 & 8) | ((k16 ^ row) & 7);
        async_load16(gbase + (colBase + row) * ZDIM + src * 16, (char*)Blds + c * 16);
      }
      __syncthreads();   // drain B (vmcnt(0) before s_barrier)
    }

    f32x4 acc[4][4];
    #pragma unroll
    for (int mi = 0; mi < 4; ++mi)
      #pragma unroll
      for (int ni = 0; ni < 4; ++ni) acc[mi][ni] = zero4;

    // 8 straight-line k-steps (K=32 each); fp8 frag = 8B/lane (ds_read_b64).
    // k-chunk CH in [0,32): LDS addr = row*256 + swz16(CH>>1, row)*16 + (CH&1)*8.
    #pragma unroll
    for (int kc = 0; kc < 4; ++kc) {
      #pragma unroll
      for (int kk2 = 0; kk2 < 2; ++kk2) {
        const int CH = kc * 8 + kk2 * 4 + quad;
        const int k16 = CH >> 1, half = (CH & 1) * 8;
        long afrag[4], bfrag[4];
        #pragma unroll
        for (int mi = 0; mi < 4; ++mi) {
          const int m = wm * 64 + mi * 16 + l16;
          const int sw = (k16 & 8) | ((k16 ^ m) & 7);
          afrag[mi] = *(const long*)((const char*)Alds + m * 256 + sw * 16 + half);
        }
        #pragma unroll
        for (int ni = 0; ni < 4; ++ni) {
          const int n = wn * 64 + ni * 16 + l16;
          const int sw = (k16 & 8) | ((k16 ^ n) & 7);
          const char* src = diag ? (const char*)Alds : (const char*)Blds;
          bfrag[ni] = *(const long*)(src + n * 256 + sw * 16 + half);
        }
        #pragma unroll
        for (int mi = 0; mi < 4; ++mi)
          #pragma unroll
          for (int ni = 0; ni < 4; ++ni)
            acc[mi][ni] = __builtin_amdgcn_mfma_f32_16x16x32_fp8_fp8(
                afrag[mi], bfrag[ni], acc[mi][ni], 0, 0, 0);
      }
    }

    // Epilogue: e = exp((s-1)/T). Rows -> rowpart regs; cols -> colred (parity dbuf)
    // -> one plain colscratch store per element. C/D layout: col=lane&15, row=quad*4+r.
    float colpart[4] = {0.0f, 0.0f, 0.0f, 0.0f};
    #pragma unroll
    for (int mi = 0; mi < 4; ++mi) {
      #pragma unroll
      for (int r = 0; r < 4; ++r) {
        const int grow = rowBase + wm * 64 + mi * 16 + quad * 4 + r;
        float s = 0.0f;
        #pragma unroll
        for (int ni = 0; ni < 4; ++ni) {
          const int gcol = colBase + wn * 64 + ni * 16 + l16;
          const float v = acc[mi][ni][r];
          const float e = exp2f((v - 1.0f) * EXP_SCALE);
          if (!diag || grow != gcol) s += e;
          colpart[ni] += e;
        }
        rowpart[mi * 4 + r] += s;
      }
    }
    if (!diag) {
      #pragma unroll
      for (int ni = 0; ni < 4; ++ni) {
        float v = colpart[ni];
        v += __shfl_xor(v, 16, 64);   // reduce across the 4 quads (frag rows)
        v += __shfl_xor(v, 32, 64);
        if (quad == 0) colred[td & 1][wm * 128 + wn * 64 + ni * 16 + l16] = v;
      }
      __syncthreads();
      if (tid < 128)
        colscratch[(jtile * 32 + (d - 1)) * 128 + tid] =
            colred[td & 1][tid] + colred[td & 1][128 + tid];
      // no barrier: next tile's top barrier orders these reads vs the next writes
    }
  }

  // Row partials: shfl over the 16 column-lanes, then merge the two wn-half waves
  // (same rows, different column halves) through LDS — per-wave stores would race.
  #pragma unroll
  for (int i = 0; i < 16; ++i) {
    float v = rowpart[i];
    v += __shfl_xor(v, 1, 64);
    v += __shfl_xor(v, 2, 64);
    v += __shfl_xor(v, 4, 64);
    v += __shfl_xor(v, 8, 64);
    rowpart[i] = v;
  }
  __syncthreads();   // colred free for reuse
  if (l16 == 0) {
    #pragma unroll
    for (int mi = 0; mi < 4; ++mi)
      #pragma unroll
      for (int r = 0; r < 4; ++r)
        colred[0][wn * 128 + wm * 64 + mi * 16 + quad * 4 + r] = rowpart[mi * 4 + r];
  }
  __syncthreads();
  if (tid < 128)
    rowscratch[(itile * 8 + chunk) * 128 + tid] = colred[0][tid] + colred[0][128 + tid];
}

// ---------------- Kernel C: gather partials per row, logf, add partial loss -------------
// Grid 64 blocks: block j handles rows [j*128,+128) and pos[j*64,+64).
// out was pre-set to 1/T by normalize; each block atomicAdds its partial (64 atomics).
__global__ __launch_bounds__(256) void reduce_kernel(
    const float* __restrict__ rowscratch, const float* __restrict__ colscratch,
    const float* __restrict__ pos, float* __restrict__ out) {
  const int j = blockIdx.x;
  const int tid = threadIdx.x;
  float v = 0.0f;
  if (tid < 128) {
    float s = 0.0f;
    #pragma unroll
    for (int c = 0; c < 8; ++c) s += rowscratch[(j * 8 + c) * 128 + tid];
    const int ns = (j < 32) ? 31 : 32;   // j<32: the d=32 pair arrived via rowscratch side
    for (int si = 0; si < ns; ++si) s += colscratch[(j * 32 + si) * 128 + tid];
    v = logf(s) * (1.0f / (float)TWO_N);
  } else if (tid < 192) {
    v = -pos[j * 64 + (tid - 128)] * (INV_T / (float)N_ROWS);
  }
  #pragma unroll
  for (int m = 1; m < 64; m <<= 1) v += __shfl_xor(v, m, 64);
  __shared__ float red[4];
  if ((tid & 63) == 0) red[tid >> 6] = v;
  __syncthreads();
  if (tid == 0) atomicAdd(out, red[0] + red[1] + red[2] + red[3]);
}

extern "C" void kernel_launch(void* const* d_in, const int* in_sizes, int n_in,
                              void* d_out, int out_size, void* d_ws, size_t ws_size,
                              hipStream_t stream) {
  const float* z1 = (const float*)d_in[0];
  const float* z2 = (const float*)d_in[1];
  char* ws = (char*)d_ws;
  unsigned char* reps = (unsigned char*)ws;                // 8192*256 = 2 MB fp8
  size_t off = (size_t)TWO_N * ZDIM;
  float* pos = (float*)(ws + off);        off += N_ROWS * 4;        // 16 KB
  float* rowscratch = (float*)(ws + off); off += 64 * 8 * 128 * 4;  // 256 KB
  float* colscratch = (float*)(ws + off); off += 64 * 32 * 128 * 4; // 1 MB

  normalize_kernel<<<N_ROWS, 256, 0, stream>>>(z1, z2, reps, pos, (float*)d_out);
  simsum_kernel<<<dim3(64, 8), 256, 0, stream>>>(reps, rowscratch, colscratch);
  reduce_kernel<<<64, 256, 0, stream>>>(rowscratch, colscratch, pos, (float*)d_out);
}

// Round 7
// 95.849 us; speedup vs baseline: 1.1828x; 1.0489x over previous
//
#include <hip/hip_runtime.h>
#include <hip/hip_bf16.h>

#define N_ROWS 4096
#define TWO_N  8192
#define ZDIM   256
#define INV_T  (1.0f/0.07f)
// exp((s-1)/T) = exp2((s-1) * INV_T * log2(e))
#define EXP_SCALE (INV_T * 1.44269504088896340736f)

typedef __attribute__((ext_vector_type(4))) float f32x4;

__device__ __forceinline__ void async_load16(const void* g, void* lds_uniform_base) {
  // HW computes LDS dest = (wave-uniform base) + lane*16; pass base WITHOUT lane term.
  __builtin_amdgcn_global_load_lds(
      (const __attribute__((address_space(1))) void*)g,
      (__attribute__((address_space(3))) void*)lds_uniform_base, 16, 0, 0);
}

// float -> OCP e4m3fn, round-to-nearest-even. Inputs here are |x| <= 1.
__device__ __forceinline__ unsigned char f32_to_e4m3(float x) {
  unsigned int u = __float_as_uint(x);
  const unsigned int s = u >> 31;
  unsigned int a = u & 0x7FFFFFFFu;
  if (a > 0x43E00000u) a = 0x43E00000u;
  const float f = __uint_as_float(a);
  unsigned int out;
  if (a < (121u << 23)) {                        // |x| < 2^-6: subnormal, step 2^-9
    const int m = (int)rintf(f * 512.0f);
    out = (unsigned int)m;
  } else {
    const unsigned int r = a + 0x7FFFFu + ((a >> 20) & 1u);  // RNE to 3 mantissa bits
    const unsigned int e8 = (r >> 23) - 120u;
    out = (e8 << 3) | ((r >> 20) & 7u);
  }
  return (unsigned char)(out | (s << 7));
}

// ---------------- Kernel A: wave-per-row normalize -> fp8 reps, fp32 pos ---------------
// 1024 blocks x 4 waves: wave handles one row of z1 AND z2. float4 loads, uchar4 stores.
__global__ __launch_bounds__(256) void normalize_kernel(
    const float* __restrict__ z1, const float* __restrict__ z2,
    unsigned char* __restrict__ reps, float* __restrict__ pos,
    float* __restrict__ out) {
  const int lane = threadIdx.x & 63;
  const int wave = threadIdx.x >> 6;
  const int r = blockIdx.x * 4 + wave;
  const float4 a = ((const float4*)(z1 + (size_t)r * ZDIM))[lane];
  const float4 b = ((const float4*)(z2 + (size_t)r * ZDIM))[lane];
  float s1 = a.x*a.x + a.y*a.y + a.z*a.z + a.w*a.w;
  float s2 = b.x*b.x + b.y*b.y + b.z*b.z + b.w*b.w;
  float s3 = a.x*b.x + a.y*b.y + a.z*b.z + a.w*b.w;
  #pragma unroll
  for (int m = 1; m < 64; m <<= 1) {
    s1 += __shfl_xor(s1, m, 64);
    s2 += __shfl_xor(s2, m, 64);
    s3 += __shfl_xor(s3, m, 64);
  }
  const float inv1 = 1.0f / fmaxf(sqrtf(s1), 1e-12f);
  const float inv2 = 1.0f / fmaxf(sqrtf(s2), 1e-12f);
  uchar4 pa, pb;
  pa.x = f32_to_e4m3(a.x * inv1); pa.y = f32_to_e4m3(a.y * inv1);
  pa.z = f32_to_e4m3(a.z * inv1); pa.w = f32_to_e4m3(a.w * inv1);
  pb.x = f32_to_e4m3(b.x * inv2); pb.y = f32_to_e4m3(b.y * inv2);
  pb.z = f32_to_e4m3(b.z * inv2); pb.w = f32_to_e4m3(b.w * inv2);
  ((uchar4*)(reps + (size_t)r * ZDIM))[lane] = pa;
  ((uchar4*)(reps + (size_t)(r + N_ROWS) * ZDIM))[lane] = pb;
  if (lane == 0) {
    pos[r] = s3 * inv1 * inv2;
    if (r == 0) out[0] = INV_T;
  }
}

// ---------------- Kernel B: triangular fp8 flash, K=128 ping-pong pipelined staging -----
// sim symmetric: each unordered 128x128 tile-pair once. Row-tile i, chunk c in 0..7:
//   c==0: d={0(diag),1,2,3} (+32 if i<32); c>0: d={4c..4c+3}; j=(i+d)&63.
// B staged in K=128 halves into ping-pong buffers; stage(q+1) is issued BEFORE compute(q),
// so the vmcnt(0) drain at the barrier ending compute(q) waits on a load that has been in
// flight for 4 k-steps of MFMA — drain exposure ~0 (AITER-style pipeline, HIP-expressible).
// LDS 32K(A) + 2x16K(B) + 2K = 66KB -> 2 blocks/CU; grid (64,8)=512 = exactly 2/CU.
// Row sums -> rowscratch (wn-halves merged via LDS at end). Col sums -> colscratch slot
// owned by exactly one block. Zero atomics.
__global__ __launch_bounds__(256, 2) void simsum_kernel(
    const unsigned char* __restrict__ reps,
    float* __restrict__ rowscratch,   // [64][8][128]
    float* __restrict__ colscratch) { // [64][32][128]
  __shared__ __align__(16) unsigned char Alds[128 * 256];     // 32 KB
  __shared__ __align__(16) unsigned char Blds[2][128 * 128];  // 2 x 16 KB
  __shared__ float colred[2][256];                            // 2 KB

  const int tid  = threadIdx.x;
  const int lane = tid & 63;
  const int wave = tid >> 6;
  const int wm = wave >> 1, wn = wave & 1;   // 2x2 wave grid
  const int quad = lane >> 4;                // 0..3
  const int l16  = lane & 15;
  const int itile = blockIdx.x;              // row tile 0..63
  const int chunk = blockIdx.y;              // distance chunk 0..7
  const int rowBase = itile * 128;
  const char* gbase = (const char*)reps;
  const bool diaghere = (chunk == 0);

  // ---- stage A tile (once): rows [rowBase,+128), 256B/row = 16 16B-chunks.
  // LDS 16B-slot (row,k16) holds global k16' = (k16&8)|((k16^row)&7)  [XOR low3 swizzle]
  {
    const int r0 = tid >> 4;                                   // 0..15
    const int src = (tid & 8) | ((tid ^ (tid >> 4)) & 7);      // swizzled source chunk
    const char* g0 = gbase + (rowBase + r0) * ZDIM + src * 16; // +p*16 rows => +p*4096
    char* l0 = (char*)Alds + (wave << 10);                     // +p*4096
    #pragma unroll
    for (int p = 0; p < 8; ++p)
      async_load16(g0 + p * 16 * ZDIM, l0 + p * 4096);
  }

  int doff[4];
  int noff;
  if (diaghere) {
    doff[0] = 1; doff[1] = 2; doff[2] = 3; doff[3] = 32;
    noff = (itile < 32) ? 4 : 3;
  } else {
    doff[0] = chunk * 4; doff[1] = chunk * 4 + 1;
    doff[2] = chunk * 4 + 2; doff[3] = chunk * 4 + 3;
    noff = 4;
  }
  const int Q = noff * 2;   // stage/compute chunk-steps: tile t = q>>1, khalf c = q&1

  // stage B chunk q: rows [jt*128,+128), k in [c*128,+128). 128B/row = 8 16B-slots,
  // slot s holds global chunk s ^ (row&7).
#define STAGE_B(q_) do {                                                        \
    const int t_ = (q_) >> 1, c_ = (q_) & 1;                                    \
    const int jt_ = (itile + doff[t_]) & 63;                                    \
    const int r0_ = tid >> 3;                              /* 0..31 */          \
    const int src_ = (tid ^ (tid >> 3)) & 7;                                    \
    const char* g0_ = gbase + (jt_ * 128 + r0_) * ZDIM + c_ * 128 + src_ * 16;  \
    char* l0_ = (char*)Blds[c_] + (wave << 10);                                 \
    _Pragma("unroll")                                                           \
    for (int p_ = 0; p_ < 4; ++p_)                                              \
      async_load16(g0_ + p_ * 32 * ZDIM, l0_ + p_ * 4096);                      \
  } while (0)

  float rowpart[16];
  #pragma unroll
  for (int i = 0; i < 16; ++i) rowpart[i] = 0.0f;
  const f32x4 zero4 = {0.0f, 0.0f, 0.0f, 0.0f};

  // ---- prologue: diag tile (if any) computed while stage(0) is in flight ----
  if (diaghere) {
    __syncthreads();                  // drain A
    if (Q > 0) STAGE_B(0);            // covered by the diag compute below
    f32x4 acc[4][4];
    #pragma unroll
    for (int mi = 0; mi < 4; ++mi)
      #pragma unroll
      for (int ni = 0; ni < 4; ++ni) acc[mi][ni] = zero4;
    #pragma unroll
    for (int w = 0; w < 8; ++w) {     // 8 K=32 windows, both operands from Alds
      const int o = w * 4 + quad;     // global k-octet of this lane
      const int k16 = o >> 1, half = (o & 1) * 8;
      long afrag[4], bfrag[4];
      #pragma unroll
      for (int mi = 0; mi < 4; ++mi) {
        const int m = wm * 64 + mi * 16 + l16;
        const int sw = (k16 & 8) | ((k16 ^ m) & 7);
        afrag[mi] = *(const long*)((const char*)Alds + m * 256 + sw * 16 + half);
      }
      #pragma unroll
      for (int ni = 0; ni < 4; ++ni) {
        const int n = wn * 64 + ni * 16 + l16;
        const int sw = (k16 & 8) | ((k16 ^ n) & 7);
        bfrag[ni] = *(const long*)((const char*)Alds + n * 256 + sw * 16 + half);
      }
      #pragma unroll
      for (int mi = 0; mi < 4; ++mi)
        #pragma unroll
        for (int ni = 0; ni < 4; ++ni)
          acc[mi][ni] = __builtin_amdgcn_mfma_f32_16x16x32_fp8_fp8(
              afrag[mi], bfrag[ni], acc[mi][ni], 0, 0, 0);
    }
    // diag epilogue: rows only, self-masked (regs only, no LDS, no barrier)
    #pragma unroll
    for (int mi = 0; mi < 4; ++mi)
      #pragma unroll
      for (int r = 0; r < 4; ++r) {
        const int grow = rowBase + wm * 64 + mi * 16 + quad * 4 + r;
        float s = 0.0f;
        #pragma unroll
        for (int ni = 0; ni < 4; ++ni) {
          const int gcol = rowBase + wn * 64 + ni * 16 + l16;
          const float e = exp2f((acc[mi][ni][r] - 1.0f) * EXP_SCALE);
          if (grow != gcol) s += e;
        }
        rowpart[mi * 4 + r] += s;
      }
    __syncthreads();                  // drain stage(0)
  } else {
    STAGE_B(0);
    __syncthreads();                  // drain A + stage(0)
  }

  // ---- pipelined main loop over chunk-steps ----
  f32x4 acc[4][4];
  for (int q = 0; q < Q; ++q) {
    if (q + 1 < Q) STAGE_B(q + 1);    // in flight during compute(q)
    const int t = q >> 1, c = q & 1;
    const int d = doff[t];
    const int jtile = (itile + d) & 63;
    const int colBase = jtile * 128;

    if (c == 0) {
      #pragma unroll
      for (int mi = 0; mi < 4; ++mi)
        #pragma unroll
        for (int ni = 0; ni < 4; ++ni) acc[mi][ni] = zero4;
    }
    // 4 K=32 windows of this K=128 half
    #pragma unroll
    for (int ws = 0; ws < 4; ++ws) {
      const int o  = c * 16 + ws * 4 + quad;   // global k-octet
      const int k16 = o >> 1, half = (o & 1) * 8;
      const int ol = ws * 4 + quad;            // chunk-local octet
      const int k16l = ol >> 1, halfl = (ol & 1) * 8;
      long afrag[4], bfrag[4];
      #pragma unroll
      for (int mi = 0; mi < 4; ++mi) {
        const int m = wm * 64 + mi * 16 + l16;
        const int sw = (k16 & 8) | ((k16 ^ m) & 7);
        afrag[mi] = *(const long*)((const char*)Alds + m * 256 + sw * 16 + half);
      }
      #pragma unroll
      for (int ni = 0; ni < 4; ++ni) {
        const int n = wn * 64 + ni * 16 + l16;
        const int sw = (k16l ^ n) & 7;
        bfrag[ni] = *(const long*)((const char*)Blds[c] + n * 128 + sw * 16 + halfl);
      }
      #pragma unroll
      for (int mi = 0; mi < 4; ++mi)
        #pragma unroll
        for (int ni = 0; ni < 4; ++ni)
          acc[mi][ni] = __builtin_amdgcn_mfma_f32_16x16x32_fp8_fp8(
              afrag[mi], bfrag[ni], acc[mi][ni], 0, 0, 0);
    }

    if (c == 1) {
      // tile complete: exp epilogue. Rows -> rowpart; cols -> colred[t&1] -> colscratch.
      float colpart[4] = {0.0f, 0.0f, 0.0f, 0.0f};
      #pragma unroll
      for (int mi = 0; mi < 4; ++mi)
        #pragma unroll
        for (int r = 0; r < 4; ++r) {
          float s = 0.0f;
          #pragma unroll
          for (int ni = 0; ni < 4; ++ni) {
            const float e = exp2f((acc[mi][ni][r] - 1.0f) * EXP_SCALE);
            s += e;
            colpart[ni] += e;
          }
          rowpart[mi * 4 + r] += s;
        }
      #pragma unroll
      for (int ni = 0; ni < 4; ++ni) {
        float v = colpart[ni];
        v += __shfl_xor(v, 16, 64);   // reduce across the 4 quads (frag rows)
        v += __shfl_xor(v, 32, 64);
        if (quad == 0) colred[t & 1][wm * 128 + wn * 64 + ni * 16 + l16] = v;
      }
      __syncthreads();   // drains stage(q+1) [in flight 4 ksteps]; colred visible; bufs free
      if (tid < 128)
        colscratch[(jtile * 32 + (d - 1)) * 128 + tid] =
            colred[t & 1][tid] + colred[t & 1][128 + tid];
      // next write to colred[t&1] is 2 barriers away (tile t+2) — safe without barrier
    } else {
      __syncthreads();   // drains stage(q+1); frees Blds[0] for stage(q+2)
    }
  }

  // ---- row partials: shfl over 16 col-lanes, merge wn-halves via LDS (they cover the
  // SAME rows — per-wave plain stores would race), one store per row ----
  #pragma unroll
  for (int i = 0; i < 16; ++i) {
    float v = rowpart[i];
    v += __shfl_xor(v, 1, 64);
    v += __shfl_xor(v, 2, 64);
    v += __shfl_xor(v, 4, 64);
    v += __shfl_xor(v, 8, 64);
    rowpart[i] = v;
  }
  __syncthreads();
  if (l16 == 0) {
    #pragma unroll
    for (int mi = 0; mi < 4; ++mi)
      #pragma unroll
      for (int r = 0; r < 4; ++r)
        colred[0][wn * 128 + wm * 64 + mi * 16 + quad * 4 + r] = rowpart[mi * 4 + r];
  }
  __syncthreads();
  if (tid < 128)
    rowscratch[(itile * 8 + chunk) * 128 + tid] = colred[0][tid] + colred[0][128 + tid];
#undef STAGE_B
}

// ---------------- Kernel C: gather partials per row, logf, add partial loss -------------
__global__ __launch_bounds__(256) void reduce_kernel(
    const float* __restrict__ rowscratch, const float* __restrict__ colscratch,
    const float* __restrict__ pos, float* __restrict__ out) {
  const int j = blockIdx.x;
  const int tid = threadIdx.x;
  float v = 0.0f;
  if (tid < 128) {
    float s = 0.0f;
    #pragma unroll
    for (int c = 0; c < 8; ++c) s += rowscratch[(j * 8 + c) * 128 + tid];
    const int ns = (j < 32) ? 31 : 32;   // j<32: the d=32 pair arrived via rowscratch side
    for (int si = 0; si < ns; ++si) s += colscratch[(j * 32 + si) * 128 + tid];
    v = logf(s) * (1.0f / (float)TWO_N);
  } else if (tid < 192) {
    v = -pos[j * 64 + (tid - 128)] * (INV_T / (float)N_ROWS);
  }
  #pragma unroll
  for (int m = 1; m < 64; m <<= 1) v += __shfl_xor(v, m, 64);
  __shared__ float red[4];
  if ((tid & 63) == 0) red[tid >> 6] = v;
  __syncthreads();
  if (tid == 0) atomicAdd(out, red[0] + red[1] + red[2] + red[3]);
}

extern "C" void kernel_launch(void* const* d_in, const int* in_sizes, int n_in,
                              void* d_out, int out_size, void* d_ws, size_t ws_size,
                              hipStream_t stream) {
  const float* z1 = (const float*)d_in[0];
  const float* z2 = (const float*)d_in[1];
  char* ws = (char*)d_ws;
  unsigned char* reps = (unsigned char*)ws;                // 8192*256 = 2 MB fp8
  size_t off = (size_t)TWO_N * ZDIM;
  float* pos = (float*)(ws + off);        off += N_ROWS * 4;        // 16 KB
  float* rowscratch = (float*)(ws + off); off += 64 * 8 * 128 * 4;  // 256 KB
  float* colscratch = (float*)(ws + off); off += 64 * 32 * 128 * 4; // 1 MB

  normalize_kernel<<<1024, 256, 0, stream>>>(z1, z2, reps, pos, (float*)d_out);
  simsum_kernel<<<dim3(64, 8), 256, 0, stream>>>(reps, rowscratch, colscratch);
  reduce_kernel<<<64, 256, 0, stream>>>(rowscratch, colscratch, pos, (float*)d_out);
}